// Round 21
// baseline (99.731 us; speedup 1.0000x reference)
//
#include <hip/hip_runtime.h>

#define Bn 2
#define Cn 3
#define Hn 160
#define Wn 160
#define SPANc 11
#define Kc 23
#define HWn (Hn * Wn)
#define PW 182                 // padded dim: 160 + 2*11
#define PP (PW * PW)
#define LAMc 0.15f
#define INVN (1.0f / (float)(Bn * HWn))
#define TJ 32                  // j-tile width (= lanes 0..31)
#define Gc 4                   // centers per thread (vertical)
#define TI 32                  // i-tile height = 8 ty-groups * Gc
#define NROW (TI + Kc - 1)     // 54 staged rows
#define NREC (NROW * TJ)       // 1728 records in LDS (16 B each = 27.6 KB)
#define CEXP (-0.72134752f)    // -0.5 * log2(e)
#define CX   (14.42695041f)    // 20 * 0.72134752  (cross-term scale)
#define CA   (0.72134752f)
#define NPREP ((Bn * PP + 255) / 256)   // 259 prep blocks

__device__ __forceinline__ float wave_reduce64(float v) {
#pragma unroll
    for (int off = 32; off > 0; off >>= 1) v += __shfl_down(v, off, 64);
    return v;
}

// pack two floats as bf16 (rne) into one uint: a in high 16, b in low 16
__device__ __forceinline__ unsigned int bf16pk(float a, float b) {
    unsigned int ua = __float_as_uint(a), ub = __float_as_uint(b);
    ua += 0x7fffu + ((ua >> 16) & 1u);
    ub += 0x7fffu + ((ub >> 16) & 1u);
    return (ua & 0xffff0000u) | (ub >> 16);
}

// Fused: zero halo + softmax/pack interior + CE block-partials (pre-scaled) + zero out.
// Record uint4: [pk(p0,p1), pk(p2,mB), pk(q0,q1), pk(q2,0)]
//   p = raw image, mB = -72.13*sum(p^2) (fp32-computed, bf16-stored), q = src*y.
// exp2 exponent identity: -0.7213*sum((c-10p)^2) = (14.427*sum(c*p)) - A - B.
__global__ __launch_bounds__(256) void prep_kernel(
    const float* __restrict__ logit, const int* __restrict__ target,
    const float* __restrict__ image, const float* __restrict__ srcmap,
    const float* __restrict__ dstmap, uint4* __restrict__ gU4,
    float4* __restrict__ cvec, float* __restrict__ pc, float* __restrict__ out)
{
    int idx = blockIdx.x * 256 + threadIdx.x;
    float ce = 0.0f;
    if (idx < Bn * PP) {
        int b   = idx / PP;
        int rem = idx - b * PP;
        int ip  = rem / PW;
        int jp  = rem - ip * PW;
        int i = ip - SPANc, j = jp - SPANc;
        if ((unsigned)i < (unsigned)Hn && (unsigned)j < (unsigned)Wn) {
            int r = i * Wn + j;
            int p = b * HWn + r;
            const float* lg = logit + (size_t)b * Cn * HWn + r;
            float l0 = lg[0], l1 = lg[HWn], l2 = lg[2 * HWn];
            float m = fmaxf(l0, fmaxf(l1, l2));
            float e0 = __expf(l0 - m), e1 = __expf(l1 - m), e2 = __expf(l2 - m);
            float s = e0 + e1 + e2;
            float inv = 1.0f / s;
            float y0 = e0 * inv, y1 = e1 * inv, y2 = e2 * inv;
            float lse = m + __logf(s);

            const float* im = image + (size_t)b * 3 * HWn + r;
            float p0 = im[0], p1 = im[HWn], p2 = im[2 * HWn];
            float sv = srcmap[p];
            float dv = dstmap[p];

            float B = (p0 * p0 + p1 * p1 + p2 * p2) * (100.0f * CA);
            gU4[idx] = make_uint4(bf16pk(p0, p1), bf16pk(p2, -B),
                                  bf16pk(sv * y0, sv * y1), bf16pk(sv * y2, 0.0f));

            float md = LAMc * (1.0f - dv) * INVN;
            cvec[p] = make_float4(md * (1.0f - y0), md * (1.0f - y1),
                                  md * (1.0f - y2), 0.0f);

            int t = target[p];
            float lt = (t == 0) ? l0 : ((t == 1) ? l1 : l2);
            ce = (lse - lt) * dv * INVN;
        } else {
            gU4[idx] = make_uint4(0u, 0u, 0u, 0u);
        }
    }
    if (idx == 0) out[0] = 0.0f;   // gcrf launches after this completes (stream order)

    float v = wave_reduce64(ce);
    __shared__ float wsum[4];
    int tid = threadIdx.x;
    if ((tid & 63) == 0) wsum[tid >> 6] = v;
    __syncthreads();
    if (tid == 0) pc[blockIdx.x] = wsum[0] + wsum[1] + wsum[2] + wsum[3];
}

// One tap: e = c.p chain seeded with mB; k = exp2(e + mA); acc. 8 VALU ops.
template<bool XY>
__device__ __forceinline__ void tap(float p0, float p1, float p2, float mB,
                                    float q0, float q1, float q2,
                                    float c0s, float c1s, float c2s, float mA,
                                    bool xy_on, float dy2, float dxv,
                                    float& e0, float& e1, float& e2)
{
    float e = fmaf(c0s, p0, fmaf(c1s, p1, fmaf(c2s, p2, mB)));
    float k = exp2f(e + mA);
    if constexpr (XY) {
        if (xy_on) k += exp2f(fmaf(dxv, dxv, dy2) * CEXP);   // 46/1150 blocks only
    }
    e0 = fmaf(k, q0, e0);
    e1 = fmaf(k, q1, e1);
    e2 = fmaf(k, q2, e2);
}

// 3-phase window loop over staged LDS records. Main loop FULLY unrolled (R21):
// lets the scheduler hoist ds_read_b128s deep (vs unroll-2's ~2 in flight) to
// cover the ~120-cyc LDS latency that 4 waves/SIMD can't hide alone.
template<bool XY>
__device__ __forceinline__ void window_loop(
    const uint4* sU4, int lbase,
    const float* c0s, const float* c1s, const float* c2s, const float* mA,
    bool xy_on, float dy2, float fi0, float eg[Gc][3])
{
#pragma unroll
    for (int r = 0; r < 3; ++r) {
        uint4 ru = sU4[lbase + r * TJ];
        float p0 = __uint_as_float(ru.x & 0xffff0000u);
        float p1 = __uint_as_float(ru.x << 16);
        float p2 = __uint_as_float(ru.y & 0xffff0000u);
        float mB = __uint_as_float(ru.y << 16);
        float q0 = __uint_as_float(ru.z & 0xffff0000u);
        float q1 = __uint_as_float(ru.z << 16);
        float q2 = __uint_as_float(ru.w & 0xffff0000u);
        float dxb = XY ? (fi0 - (fi0 + (float)(r - SPANc)) * (1.0f / 6.0f)) : 0.0f;
#pragma unroll
        for (int c = 0; c < 3; ++c) {
            if (c > r) continue;
            tap<XY>(p0, p1, p2, mB, q0, q1, q2, c0s[c], c1s[c], c2s[c], mA[c],
                    xy_on, dy2, dxb + (float)c, eg[c][0], eg[c][1], eg[c][2]);
        }
    }
#pragma unroll
    for (int r = 3; r <= 22; ++r) {
        uint4 ru = sU4[lbase + r * TJ];
        float p0 = __uint_as_float(ru.x & 0xffff0000u);
        float p1 = __uint_as_float(ru.x << 16);
        float p2 = __uint_as_float(ru.y & 0xffff0000u);
        float mB = __uint_as_float(ru.y << 16);
        float q0 = __uint_as_float(ru.z & 0xffff0000u);
        float q1 = __uint_as_float(ru.z << 16);
        float q2 = __uint_as_float(ru.w & 0xffff0000u);
        float dxb = XY ? (fi0 - (fi0 + (float)(r - SPANc)) * (1.0f / 6.0f)) : 0.0f;
#pragma unroll
        for (int c = 0; c < Gc; ++c) {
            tap<XY>(p0, p1, p2, mB, q0, q1, q2, c0s[c], c1s[c], c2s[c], mA[c],
                    xy_on, dy2, dxb + (float)c, eg[c][0], eg[c][1], eg[c][2]);
        }
    }
#pragma unroll
    for (int r = 23; r <= 25; ++r) {
        uint4 ru = sU4[lbase + r * TJ];
        float p0 = __uint_as_float(ru.x & 0xffff0000u);
        float p1 = __uint_as_float(ru.x << 16);
        float p2 = __uint_as_float(ru.y & 0xffff0000u);
        float mB = __uint_as_float(ru.y << 16);
        float q0 = __uint_as_float(ru.z & 0xffff0000u);
        float q1 = __uint_as_float(ru.z << 16);
        float q2 = __uint_as_float(ru.w & 0xffff0000u);
        float dxb = XY ? (fi0 - (fi0 + (float)(r - SPANc)) * (1.0f / 6.0f)) : 0.0f;
#pragma unroll
        for (int c = 1; c < Gc; ++c) {
            if (c < r - 22) continue;
            tap<XY>(p0, p1, p2, mB, q0, q1, q2, c0s[c], c1s[c], c2s[c], mA[c],
                    xy_on, dy2, dxb + (float)c, eg[c][0], eg[c][1], eg[c][2]);
        }
    }
}

// Window kernel. Grid: (5, 5*B, 23) = 1150 blocks. Block (32,8). One dj per block.
// Stage 54x32 uint4 records (27.6 KB LDS, single ds_read_b128 per record).
// Each block float-atomicAdds its pre-scaled contribution into out[0].
// One designated non-XY block also reduces the 259 CE partials.
__global__ __launch_bounds__(256, 4) void gcrf_kernel(
    const uint4* __restrict__ gU4, const float4* __restrict__ cvec,
    const float* __restrict__ pc, float* __restrict__ out)
{
    __shared__ uint4 sU4[NREC];

    int tx = threadIdx.x;                 // 0..31 (j)
    int ty = threadIdx.y;                 // 0..7  (i-group)
    int tid = ty * TJ + tx;
    int jx = blockIdx.x;
    int j  = jx * TJ + tx;
    int by = blockIdx.y;
    int b  = by / 5;
    int it = by - b * 5;
    int i0g = it * TI + ty * Gc;          // first center row of this thread
    int dj = blockIdx.z;                  // 0..22

    size_t g0 = (size_t)b * PP + (size_t)(it * TI) * PW + (jx * TJ + dj);
    for (int n = tid; n < NREC; n += 256) {
        int rr = n >> 5, cc = n & 31;
        sU4[n] = gU4[g0 + (size_t)rr * PW + cc];
    }
    __syncthreads();

    int lbase = ty * Gc * TJ + tx;        // LDS index of (local row ty*Gc, col tx)
    float c0s[Gc], c1s[Gc], c2s[Gc], mA[Gc];
#pragma unroll
    for (int c = 0; c < Gc; ++c) {
        uint4 cu = sU4[lbase + (c + SPANc) * TJ];
        float cc0 = __uint_as_float(cu.x & 0xffff0000u);
        float cc1 = __uint_as_float(cu.x << 16);
        float cc2 = __uint_as_float(cu.y & 0xffff0000u);
        c0s[c] = cc0 * CX; c1s[c] = cc1 * CX; c2s[c] = cc2 * CX;
        mA[c] = -CA * fmaf(cc0, cc0, fmaf(cc1, cc1, cc2 * cc2));
    }

    // k_xy < 2.3e-29 unless both i<16 and j<16 (source-bug form: d = c - p/6)
    bool xy_on = (j < 16) && (i0g < 16);
    float dy = (float)j - (float)(j + dj - SPANc) * (1.0f / 6.0f);
    float dy2 = dy * dy;
    float fi0 = (float)i0g;

    float eg[Gc][3];
#pragma unroll
    for (int c = 0; c < Gc; ++c) { eg[c][0] = 0.f; eg[c][1] = 0.f; eg[c][2] = 0.f; }

    if (jx == 0 && it == 0) {   // block-uniform: only blocks where xy_on can hold
        window_loop<true>(sU4, lbase, c0s, c1s, c2s, mA, xy_on, dy2, fi0, eg);
    } else {
        window_loop<false>(sU4, lbase, c0s, c1s, c2s, mA, false, dy2, fi0, eg);
    }

    // epilogue: cvec already holds lam*(1-dst)*(1-y_c)/(B*HW)
    const float4* cv = cvec + ((size_t)b * HWn + (size_t)i0g * Wn + j);
    float contrib = 0.0f;
#pragma unroll
    for (int c = 0; c < Gc; ++c) {
        float4 t = cv[(size_t)c * Wn];
        contrib += eg[c][0] * t.x + eg[c][1] * t.y + eg[c][2] * t.z;
    }

    float v = wave_reduce64(contrib);
    __shared__ float wsum[4];
    if ((tid & 63) == 0) wsum[tid >> 6] = v;
    __syncthreads();
    if (tid == 0) atomicAdd(out, wsum[0] + wsum[1] + wsum[2] + wsum[3]);

    // designated non-XY block folds in the (pre-scaled) CE partial sums
    if (jx == 4 && by == 9 && dj == 22) {
        float s = 0.0f;
        if (tid < NPREP) s += pc[tid];
        if (tid + 256 < NPREP) s += pc[tid + 256];
        float v2 = wave_reduce64(s);
        __syncthreads();
        if ((tid & 63) == 0) wsum[tid >> 6] = v2;
        __syncthreads();
        if (tid == 0) atomicAdd(out, wsum[0] + wsum[1] + wsum[2] + wsum[3]);
    }
}

extern "C" void kernel_launch(void* const* d_in, const int* in_sizes, int n_in,
                              void* d_out, int out_size, void* d_ws, size_t ws_size,
                              hipStream_t stream)
{
    const float* logit  = (const float*)d_in[0];
    const int*   target = (const int*)d_in[1];
    const float* image  = (const float*)d_in[2];
    const float* srcmap = (const float*)d_in[3];
    const float* dstmap = (const float*)d_in[4];
    float* out = (float*)d_out;

    const size_t NRECG = (size_t)Bn * PP;   // 66,248 padded records
    float*  pc   = (float*)((char*)d_ws + 256);                  // 259 CE partials
    uint4*  gU4  = (uint4*)((char*)d_ws + 4096);
    float4* cvec = (float4*)((char*)d_ws + 4096 + NRECG * 16);

    prep_kernel<<<NPREP, 256, 0, stream>>>(logit, target, image, srcmap, dstmap,
                                           gU4, cvec, pc, out);
    dim3 grid(Wn / TJ, (Hn / TI) * Bn, Kc);
    dim3 blk(TJ, 8);
    gcrf_kernel<<<grid, blk, 0, stream>>>(gU4, cvec, pc, out);
}

// Round 22
// 85.676 us; speedup vs baseline: 1.1640x; 1.1640x over previous
//
#include <hip/hip_runtime.h>

#define Bn 2
#define Cn 3
#define Hn 160
#define Wn 160
#define SPANc 11
#define Kc 23
#define HWn (Hn * Wn)
#define PW 182                 // padded dim: 160 + 2*11
#define PP (PW * PW)
#define LAMc 0.15f
#define INVN (1.0f / (float)(Bn * HWn))
#define TJ 32                  // j-tile width (= lanes 0..31)
#define Gc 4                   // centers per thread (vertical)
#define TI 32                  // i-tile height = 8 ty-groups * Gc
#define NROW (TI + Kc - 1)     // 54 staged rows
#define NREC (NROW * TJ)       // 1728 records in LDS (16 B each = 27.6 KB)
#define CEXP (-0.72134752f)    // -0.5 * log2(e)
#define CX   (14.42695041f)    // 20 * 0.72134752  (cross-term scale)
#define CA   (0.72134752f)
#define NPREP ((Bn * PP + 255) / 256)   // 259 prep blocks

__device__ __forceinline__ float wave_reduce64(float v) {
#pragma unroll
    for (int off = 32; off > 0; off >>= 1) v += __shfl_down(v, off, 64);
    return v;
}

// pack two floats as bf16 (rne) into one uint: a in high 16, b in low 16
__device__ __forceinline__ unsigned int bf16pk(float a, float b) {
    unsigned int ua = __float_as_uint(a), ub = __float_as_uint(b);
    ua += 0x7fffu + ((ua >> 16) & 1u);
    ub += 0x7fffu + ((ub >> 16) & 1u);
    return (ua & 0xffff0000u) | (ub >> 16);
}

// Fused: zero halo + softmax/pack interior + CE block-partials (pre-scaled) + zero out.
// Record uint4: [pk(p0,p1), pk(p2,mB), pk(q0,q1), pk(q2,0)]
//   p = raw image, mB = -72.13*sum(p^2) (fp32-computed, bf16-stored), q = src*y.
// exp2 exponent identity: -0.7213*sum((c-10p)^2) = (14.427*sum(c*p)) - A - B.
__global__ __launch_bounds__(256) void prep_kernel(
    const float* __restrict__ logit, const int* __restrict__ target,
    const float* __restrict__ image, const float* __restrict__ srcmap,
    const float* __restrict__ dstmap, uint4* __restrict__ gU4,
    float4* __restrict__ cvec, float* __restrict__ pc, float* __restrict__ out)
{
    int idx = blockIdx.x * 256 + threadIdx.x;
    float ce = 0.0f;
    if (idx < Bn * PP) {
        int b   = idx / PP;
        int rem = idx - b * PP;
        int ip  = rem / PW;
        int jp  = rem - ip * PW;
        int i = ip - SPANc, j = jp - SPANc;
        if ((unsigned)i < (unsigned)Hn && (unsigned)j < (unsigned)Wn) {
            int r = i * Wn + j;
            int p = b * HWn + r;
            const float* lg = logit + (size_t)b * Cn * HWn + r;
            float l0 = lg[0], l1 = lg[HWn], l2 = lg[2 * HWn];
            float m = fmaxf(l0, fmaxf(l1, l2));
            float e0 = __expf(l0 - m), e1 = __expf(l1 - m), e2 = __expf(l2 - m);
            float s = e0 + e1 + e2;
            float inv = 1.0f / s;
            float y0 = e0 * inv, y1 = e1 * inv, y2 = e2 * inv;
            float lse = m + __logf(s);

            const float* im = image + (size_t)b * 3 * HWn + r;
            float p0 = im[0], p1 = im[HWn], p2 = im[2 * HWn];
            float sv = srcmap[p];
            float dv = dstmap[p];

            float B = (p0 * p0 + p1 * p1 + p2 * p2) * (100.0f * CA);
            gU4[idx] = make_uint4(bf16pk(p0, p1), bf16pk(p2, -B),
                                  bf16pk(sv * y0, sv * y1), bf16pk(sv * y2, 0.0f));

            float md = LAMc * (1.0f - dv) * INVN;
            cvec[p] = make_float4(md * (1.0f - y0), md * (1.0f - y1),
                                  md * (1.0f - y2), 0.0f);

            int t = target[p];
            float lt = (t == 0) ? l0 : ((t == 1) ? l1 : l2);
            ce = (lse - lt) * dv * INVN;
        } else {
            gU4[idx] = make_uint4(0u, 0u, 0u, 0u);
        }
    }
    if (idx == 0) out[0] = 0.0f;   // gcrf launches after this completes (stream order)

    float v = wave_reduce64(ce);
    __shared__ float wsum[4];
    int tid = threadIdx.x;
    if ((tid & 63) == 0) wsum[tid >> 6] = v;
    __syncthreads();
    if (tid == 0) pc[blockIdx.x] = wsum[0] + wsum[1] + wsum[2] + wsum[3];
}

// One tap: e = c.p chain seeded with mB; k = exp2(e + mA); acc. 8 VALU ops.
template<bool XY>
__device__ __forceinline__ void tap(float p0, float p1, float p2, float mB,
                                    float q0, float q1, float q2,
                                    float c0s, float c1s, float c2s, float mA,
                                    bool xy_on, float dy2, float dxv,
                                    float& e0, float& e1, float& e2)
{
    float e = fmaf(c0s, p0, fmaf(c1s, p1, fmaf(c2s, p2, mB)));
    float k = exp2f(e + mA);
    if constexpr (XY) {
        if (xy_on) k += exp2f(fmaf(dxv, dxv, dy2) * CEXP);   // 46/1150 blocks only
    }
    e0 = fmaf(k, q0, e0);
    e1 = fmaf(k, q1, e1);
    e2 = fmaf(k, q2, e2);
}

// 3-phase window loop over staged LDS records. Main loop unroll-4 (R22): ~4-5
// uint4 loads in flight (vs 2 at unroll-2, vs spill at full unroll-20/R21).
template<bool XY>
__device__ __forceinline__ void window_loop(
    const uint4* sU4, int lbase,
    const float* c0s, const float* c1s, const float* c2s, const float* mA,
    bool xy_on, float dy2, float fi0, float eg[Gc][3])
{
#pragma unroll
    for (int r = 0; r < 3; ++r) {
        uint4 ru = sU4[lbase + r * TJ];
        float p0 = __uint_as_float(ru.x & 0xffff0000u);
        float p1 = __uint_as_float(ru.x << 16);
        float p2 = __uint_as_float(ru.y & 0xffff0000u);
        float mB = __uint_as_float(ru.y << 16);
        float q0 = __uint_as_float(ru.z & 0xffff0000u);
        float q1 = __uint_as_float(ru.z << 16);
        float q2 = __uint_as_float(ru.w & 0xffff0000u);
        float dxb = XY ? (fi0 - (fi0 + (float)(r - SPANc)) * (1.0f / 6.0f)) : 0.0f;
#pragma unroll
        for (int c = 0; c < 3; ++c) {
            if (c > r) continue;
            tap<XY>(p0, p1, p2, mB, q0, q1, q2, c0s[c], c1s[c], c2s[c], mA[c],
                    xy_on, dy2, dxb + (float)c, eg[c][0], eg[c][1], eg[c][2]);
        }
    }
#pragma unroll 4
    for (int r = 3; r <= 22; ++r) {
        uint4 ru = sU4[lbase + r * TJ];
        float p0 = __uint_as_float(ru.x & 0xffff0000u);
        float p1 = __uint_as_float(ru.x << 16);
        float p2 = __uint_as_float(ru.y & 0xffff0000u);
        float mB = __uint_as_float(ru.y << 16);
        float q0 = __uint_as_float(ru.z & 0xffff0000u);
        float q1 = __uint_as_float(ru.z << 16);
        float q2 = __uint_as_float(ru.w & 0xffff0000u);
        float dxb = XY ? (fi0 - (fi0 + (float)(r - SPANc)) * (1.0f / 6.0f)) : 0.0f;
#pragma unroll
        for (int c = 0; c < Gc; ++c) {
            tap<XY>(p0, p1, p2, mB, q0, q1, q2, c0s[c], c1s[c], c2s[c], mA[c],
                    xy_on, dy2, dxb + (float)c, eg[c][0], eg[c][1], eg[c][2]);
        }
    }
#pragma unroll
    for (int r = 23; r <= 25; ++r) {
        uint4 ru = sU4[lbase + r * TJ];
        float p0 = __uint_as_float(ru.x & 0xffff0000u);
        float p1 = __uint_as_float(ru.x << 16);
        float p2 = __uint_as_float(ru.y & 0xffff0000u);
        float mB = __uint_as_float(ru.y << 16);
        float q0 = __uint_as_float(ru.z & 0xffff0000u);
        float q1 = __uint_as_float(ru.z << 16);
        float q2 = __uint_as_float(ru.w & 0xffff0000u);
        float dxb = XY ? (fi0 - (fi0 + (float)(r - SPANc)) * (1.0f / 6.0f)) : 0.0f;
#pragma unroll
        for (int c = 1; c < Gc; ++c) {
            if (c < r - 22) continue;
            tap<XY>(p0, p1, p2, mB, q0, q1, q2, c0s[c], c1s[c], c2s[c], mA[c],
                    xy_on, dy2, dxb + (float)c, eg[c][0], eg[c][1], eg[c][2]);
        }
    }
}

// Window kernel. Grid: (5, 5*B, 23) = 1150 blocks. Block (32,8). One dj per block.
// Stage 54x32 uint4 records (27.6 KB LDS, single ds_read_b128 per record).
// Each block float-atomicAdds its pre-scaled contribution into out[0].
// One designated non-XY block also reduces the 259 CE partials.
__global__ __launch_bounds__(256, 4) void gcrf_kernel(
    const uint4* __restrict__ gU4, const float4* __restrict__ cvec,
    const float* __restrict__ pc, float* __restrict__ out)
{
    __shared__ uint4 sU4[NREC];

    int tx = threadIdx.x;                 // 0..31 (j)
    int ty = threadIdx.y;                 // 0..7  (i-group)
    int tid = ty * TJ + tx;
    int jx = blockIdx.x;
    int j  = jx * TJ + tx;
    int by = blockIdx.y;
    int b  = by / 5;
    int it = by - b * 5;
    int i0g = it * TI + ty * Gc;          // first center row of this thread
    int dj = blockIdx.z;                  // 0..22

    size_t g0 = (size_t)b * PP + (size_t)(it * TI) * PW + (jx * TJ + dj);
    for (int n = tid; n < NREC; n += 256) {
        int rr = n >> 5, cc = n & 31;
        sU4[n] = gU4[g0 + (size_t)rr * PW + cc];
    }
    __syncthreads();

    int lbase = ty * Gc * TJ + tx;        // LDS index of (local row ty*Gc, col tx)
    float c0s[Gc], c1s[Gc], c2s[Gc], mA[Gc];
#pragma unroll
    for (int c = 0; c < Gc; ++c) {
        uint4 cu = sU4[lbase + (c + SPANc) * TJ];
        float cc0 = __uint_as_float(cu.x & 0xffff0000u);
        float cc1 = __uint_as_float(cu.x << 16);
        float cc2 = __uint_as_float(cu.y & 0xffff0000u);
        c0s[c] = cc0 * CX; c1s[c] = cc1 * CX; c2s[c] = cc2 * CX;
        mA[c] = -CA * fmaf(cc0, cc0, fmaf(cc1, cc1, cc2 * cc2));
    }

    // k_xy < 2.3e-29 unless both i<16 and j<16 (source-bug form: d = c - p/6)
    bool xy_on = (j < 16) && (i0g < 16);
    float dy = (float)j - (float)(j + dj - SPANc) * (1.0f / 6.0f);
    float dy2 = dy * dy;
    float fi0 = (float)i0g;

    float eg[Gc][3];
#pragma unroll
    for (int c = 0; c < Gc; ++c) { eg[c][0] = 0.f; eg[c][1] = 0.f; eg[c][2] = 0.f; }

    if (jx == 0 && it == 0) {   // block-uniform: only blocks where xy_on can hold
        window_loop<true>(sU4, lbase, c0s, c1s, c2s, mA, xy_on, dy2, fi0, eg);
    } else {
        window_loop<false>(sU4, lbase, c0s, c1s, c2s, mA, false, dy2, fi0, eg);
    }

    // epilogue: cvec already holds lam*(1-dst)*(1-y_c)/(B*HW)
    const float4* cv = cvec + ((size_t)b * HWn + (size_t)i0g * Wn + j);
    float contrib = 0.0f;
#pragma unroll
    for (int c = 0; c < Gc; ++c) {
        float4 t = cv[(size_t)c * Wn];
        contrib += eg[c][0] * t.x + eg[c][1] * t.y + eg[c][2] * t.z;
    }

    float v = wave_reduce64(contrib);
    __shared__ float wsum[4];
    if ((tid & 63) == 0) wsum[tid >> 6] = v;
    __syncthreads();
    if (tid == 0) atomicAdd(out, wsum[0] + wsum[1] + wsum[2] + wsum[3]);

    // designated non-XY block folds in the (pre-scaled) CE partial sums
    if (jx == 4 && by == 9 && dj == 22) {
        float s = 0.0f;
        if (tid < NPREP) s += pc[tid];
        if (tid + 256 < NPREP) s += pc[tid + 256];
        float v2 = wave_reduce64(s);
        __syncthreads();
        if ((tid & 63) == 0) wsum[tid >> 6] = v2;
        __syncthreads();
        if (tid == 0) atomicAdd(out, wsum[0] + wsum[1] + wsum[2] + wsum[3]);
    }
}

extern "C" void kernel_launch(void* const* d_in, const int* in_sizes, int n_in,
                              void* d_out, int out_size, void* d_ws, size_t ws_size,
                              hipStream_t stream)
{
    const float* logit  = (const float*)d_in[0];
    const int*   target = (const int*)d_in[1];
    const float* image  = (const float*)d_in[2];
    const float* srcmap = (const float*)d_in[3];
    const float* dstmap = (const float*)d_in[4];
    float* out = (float*)d_out;

    const size_t NRECG = (size_t)Bn * PP;   // 66,248 padded records
    float*  pc   = (float*)((char*)d_ws + 256);                  // 259 CE partials
    uint4*  gU4  = (uint4*)((char*)d_ws + 4096);
    float4* cvec = (float4*)((char*)d_ws + 4096 + NRECG * 16);

    prep_kernel<<<NPREP, 256, 0, stream>>>(logit, target, image, srcmap, dstmap,
                                           gU4, cvec, pc, out);
    dim3 grid(Wn / TJ, (Hn / TI) * Bn, Kc);
    dim3 blk(TJ, 8);
    gcrf_kernel<<<grid, blk, 0, stream>>>(gU4, cvec, pc, out);
}